// Round 3
// baseline (100404.883 us; speedup 1.0000x reference)
//
#include <hip/hip_runtime.h>
#include <float.h>

// Batched transducer greedy decode, B=32 T=1000 H=640 V=5000, fp32.
// Persistent cooperative-style kernel: 240 blocks x 512 thr, 2 grid barriers/step.
#define BB 32
#define TT 1000
#define HH 640
#define H4 2560
#define VV 5000
#define NLOG 157   // logits tiles, 32 cols each (last tile 8 valid)
#define NWH  80    // h@Wh tiles, 32 cols each
#define NB   240   // persistent grid (8 barrier groups x 30)

// workspace layout (float offsets)
#define O_JOINT 0        // jointT[j][b]  (640x32)
#define O_HT    20480    // hT[j][b]      (640x32)
#define O_HWH   40960    // hwhT[col][b]  (2560x32)
#define O_CT    122880   // cT[j][b]
#define O_PNT   143360   // pnT[j][b]
#define O_PM    163840   // partial max    [157*32]
#define O_PS    168864   // partial sumexp [157*32]
#define O_PI    173888   // partial argmax [157*32] (int bits)
#define O_BAR   179008   // barrier: 17 slots x 16 u32 (64B apart)
#define O_XWXB  180224   // embed@Wx + b  (5000x2560), optional
#define XWXB_ELEMS ((size_t)VV * (size_t)H4)

__device__ __forceinline__ float sigf(float x) { return 1.0f / (1.0f + expf(-x)); }

// ---- two-level grid barrier: 8 cnt lines (30 blocks each) -> root -> 8 gen lines
__device__ __forceinline__ void grid_bar(unsigned* bar, unsigned target) {
  __syncthreads();
  if (threadIdx.x == 0) {
    const int g = (int)blockIdx.x / 30;  // 0..7
    unsigned* cnt  = bar + g * 16;
    unsigned* root = bar + 8 * 16;
    unsigned* gen  = bar + (9 + g) * 16;
    __threadfence();
    unsigned a = __hip_atomic_fetch_add(cnt, 1u, __ATOMIC_ACQ_REL, __HIP_MEMORY_SCOPE_AGENT);
    bool done = false;
    if (a == 29u) {  // last of my group
      unsigned r = __hip_atomic_fetch_add(root, 1u, __ATOMIC_ACQ_REL, __HIP_MEMORY_SCOPE_AGENT);
      if (r == 7u) {  // global last: reset, then release all gen lines
        __hip_atomic_store(root, 0u, __ATOMIC_RELAXED, __HIP_MEMORY_SCOPE_AGENT);
#pragma unroll
        for (int i = 0; i < 8; ++i)
          __hip_atomic_store(bar + i * 16, 0u, __ATOMIC_RELAXED, __HIP_MEMORY_SCOPE_AGENT);
#pragma unroll
        for (int i = 0; i < 8; ++i)
          __hip_atomic_store(bar + (9 + i) * 16, target, __ATOMIC_RELEASE, __HIP_MEMORY_SCOPE_AGENT);
        done = true;
      }
    }
    if (!done) {
      while (__hip_atomic_load(gen, __ATOMIC_ACQUIRE, __HIP_MEMORY_SCOPE_AGENT) < target)
        __builtin_amdgcn_s_sleep(2);
    }
    __threadfence();
  }
  __syncthreads();
}

// ---------------- precompute: xwxb[v][c] = sum_k embed[v][k]*Wx[k][c] + b[c]
__global__ __launch_bounds__(256) void precompute_k(const float* __restrict__ embed,
                                                    const float* __restrict__ Wx,
                                                    const float* __restrict__ bias,
                                                    float* __restrict__ xwxb) {
  __shared__ float embT[HH * 17];
  const int tid = threadIdx.x;
  const int v0 = blockIdx.y * 16;
  const int c0 = blockIdx.x * 256 + (tid & 63) * 4;
  const int vg = tid >> 6;
  for (int i = tid; i < 16 * 160; i += 256) {
    int vr = i / 160, kq = i - vr * 160;
    int v = v0 + vr; if (v >= VV) v = VV - 1;
    float4 e = *(const float4*)&embed[(size_t)v * HH + kq * 4];
    embT[(kq * 4 + 0) * 17 + vr] = e.x;
    embT[(kq * 4 + 1) * 17 + vr] = e.y;
    embT[(kq * 4 + 2) * 17 + vr] = e.z;
    embT[(kq * 4 + 3) * 17 + vr] = e.w;
  }
  __syncthreads();
  float acc[16];
#pragma unroll
  for (int i = 0; i < 16; ++i) acc[i] = 0.f;
#pragma unroll 4
  for (int k = 0; k < HH; ++k) {
    float4 wv = *(const float4*)&Wx[(size_t)k * H4 + c0];
#pragma unroll
    for (int i = 0; i < 4; ++i) {
      float e = embT[k * 17 + vg * 4 + i];
      acc[i * 4 + 0] += e * wv.x;
      acc[i * 4 + 1] += e * wv.y;
      acc[i * 4 + 2] += e * wv.z;
      acc[i * 4 + 3] += e * wv.w;
    }
  }
  float4 bv = *(const float4*)&bias[c0];
#pragma unroll
  for (int i = 0; i < 4; ++i) {
    int v = v0 + vg * 4 + i;
    if (v < VV) {
      float4 r;
      r.x = acc[i * 4 + 0] + bv.x; r.y = acc[i * 4 + 1] + bv.y;
      r.z = acc[i * 4 + 2] + bv.z; r.w = acc[i * 4 + 3] + bv.w;
      *(float4*)&xwxb[(size_t)v * H4 + c0] = r;
    }
  }
}

// ---------------- init: barrier zero + initial LSTM step (h0=c0=0, tok=0) + joint t=0
__global__ __launch_bounds__(256) void init_k(const float* __restrict__ tn,
                                              const float* __restrict__ embed,
                                              const float* __restrict__ Wx,
                                              const float* __restrict__ bias,
                                              float* ws, int use_table) {
  const int tid = threadIdx.x, bid = blockIdx.x;
  const int b = tid & 31, c8 = tid >> 5;
  const int j = bid * 8 + c8;
  if (bid == 0) {
    unsigned* bar = (unsigned*)(ws + O_BAR);
    for (int i = tid; i < 17 * 16; i += 256) bar[i] = 0u;
  }
  const float* xwxb = ws + O_XWXB;
  float g4[4];
  if (use_table) {
#pragma unroll
    for (int g = 0; g < 4; ++g) g4[g] = xwxb[g * HH + j];  // token 0 row
  } else {
#pragma unroll
    for (int g = 0; g < 4; ++g) g4[g] = bias[g * HH + j];
#pragma unroll 4
    for (int k = 0; k < HH; ++k) {
      float xv = embed[k];  // token 0 row
#pragma unroll
      for (int g = 0; g < 4; ++g) g4[g] += xv * Wx[(size_t)k * H4 + g * HH + j];
    }
  }
  float c1 = sigf(g4[0]) * tanhf(g4[2]);
  float h1 = sigf(g4[3]) * tanhf(c1);
  ws[O_CT + j * 32 + b] = c1;
  ws[O_HT + j * 32 + b] = h1;
  ws[O_PNT + j * 32 + b] = h1;
  ws[O_JOINT + j * 32 + b] = tanhf(tn[(size_t)b * TT * HH + j] + h1);
}

// ---------------- persistent decode kernel
__global__ __launch_bounds__(512, 2) void decode_k(const float* __restrict__ tn,
                                                   const float* __restrict__ embed,
                                                   const float* __restrict__ Wx,
                                                   const float* __restrict__ bias,
                                                   const float* __restrict__ Wh,
                                                   const float* __restrict__ Wc,
                                                   const float* __restrict__ bc,
                                                   float* __restrict__ out,
                                                   float* ws, int use_table) {
  __shared__ float smem[10288];  // phase A: part[8704]+lm/lsv/lix[3*528]; phase B: rm/rs/ri/gmat/xl
  __shared__ int s_tok[32];      // token chosen this step
  __shared__ int s_upd[32];
  __shared__ int s_ptok[32];     // persistent previous token (per-block copy)
  __shared__ float s_scores[32]; // block 0 only
  const int tid = threadIdx.x, bid = blockIdx.x;
  unsigned* bar = (unsigned*)(ws + O_BAR);
  const float* xwxb = ws + O_XWXB;

  if (tid < 32) { s_ptok[tid] = 0; s_scores[tid] = 0.f; }
  __syncthreads();

  unsigned epoch = 0;
  for (int t = 0; t < TT; ++t) {
    // ================= phase A: logits GEMM partials + h@Wh GEMM =================
    if (bid < NLOG + NWH) {
      float* part = smem;                 // [8][col32*34 + b]
      float* lm = smem + 8704;
      float* lsv = smem + 8704 + 528;
      int* lix = (int*)(smem + 8704 + 1056);
      const int lane = tid & 63, wv = tid >> 6;
      const int sub = lane >> 5, col = lane & 31;
      const int kbase = (wv * 2 + sub) * 40;  // 16-way K split
      const bool is_log = (bid < NLOG);

      float acc[32];
#pragma unroll
      for (int i = 0; i < 32; ++i) acc[i] = 0.f;

      if (is_log) {
        const int c = bid * 32 + col;
        const int cc = (c < VV) ? c : (VV - 1);
        const float* jb = ws + O_JOINT + kbase * 32;
        const float* wp = Wc + (size_t)kbase * VV + cc;
#pragma unroll 4
        for (int kk = 0; kk < 40; ++kk) {
          float w = wp[(size_t)kk * VV];
          const float4* jp = (const float4*)(jb + kk * 32);
#pragma unroll
          for (int r = 0; r < 8; ++r) {
            float4 j4 = jp[r];
            acc[r * 4 + 0] += j4.x * w; acc[r * 4 + 1] += j4.y * w;
            acc[r * 4 + 2] += j4.z * w; acc[r * 4 + 3] += j4.w * w;
          }
        }
      } else {
        const int c = (bid - NLOG) * 32 + col;
        const float* hb = ws + O_HT + kbase * 32;
        const float* wp = Wh + (size_t)kbase * H4 + c;
#pragma unroll 4
        for (int kk = 0; kk < 40; ++kk) {
          float w = wp[(size_t)kk * H4];
          const float4* jp = (const float4*)(hb + kk * 32);
#pragma unroll
          for (int r = 0; r < 8; ++r) {
            float4 j4 = jp[r];
            acc[r * 4 + 0] += j4.x * w; acc[r * 4 + 1] += j4.y * w;
            acc[r * 4 + 2] += j4.z * w; acc[r * 4 + 3] += j4.w * w;
          }
        }
      }
#pragma unroll
      for (int i = 0; i < 32; ++i) acc[i] += __shfl_xor(acc[i], 32);
      if (sub == 0) {
        float* pb = part + wv * 1088 + col * 34;
#pragma unroll
        for (int r2 = 0; r2 < 16; ++r2)
          *(float2*)&pb[r2 * 2] = make_float2(acc[r2 * 2], acc[r2 * 2 + 1]);
      }
      __syncthreads();

      const int b = tid & 31, colg = tid >> 5;
      float lg[2];
#pragma unroll
      for (int i = 0; i < 2; ++i) {
        const int cl = colg * 2 + i;
        float s = 0.f;
#pragma unroll
        for (int q = 0; q < 8; ++q) s += part[q * 1088 + cl * 34 + b];
        lg[i] = s;
      }
      if (is_log) {
        float m = -FLT_MAX; int ix = 0;
        float lv[2];
#pragma unroll
        for (int i = 0; i < 2; ++i) {
          int cg = bid * 32 + colg * 2 + i;
          int cgc = (cg < VV) ? cg : (VV - 1);
          float l = (cg < VV) ? lg[i] + bc[cgc] : -FLT_MAX;
          lv[i] = l;
          if (l > m) { m = l; ix = cg; }
        }
        float e = 0.f;
        if (m > -FLT_MAX) {
#pragma unroll
          for (int i = 0; i < 2; ++i) e += expf(lv[i] - m);
        }
        lm[colg * 33 + b] = m; lsv[colg * 33 + b] = e; lix[colg * 33 + b] = ix;
        __syncthreads();
        if (tid < 32) {
          float m2 = lm[tid], s2 = lsv[tid]; int ix2 = lix[tid];
#pragma unroll
          for (int q = 1; q < 16; ++q) {
            float M = lm[q * 33 + tid], S = lsv[q * 33 + tid]; int I = lix[q * 33 + tid];
            if (M > m2) { s2 = s2 * expf(m2 - M) + S; m2 = M; ix2 = I; }
            else if (M > -FLT_MAX) { s2 += S * expf(M - m2); }
          }
          ws[O_PM + bid * 32 + tid] = m2;
          ws[O_PS + bid * 32 + tid] = s2;
          ws[O_PI + bid * 32 + tid] = __int_as_float(ix2);
        }
      } else {
        const int chb = (bid - NLOG) * 32 + colg * 2;
#pragma unroll
        for (int i = 0; i < 2; ++i)
          ws[O_HWH + (chb + i) * 32 + b] = lg[i];
      }
    }
    epoch++; grid_bar(bar, epoch);

    // ================= phase B: reduce -> token ; gates ; state update ; next joint =================
    if (bid < 160) {
      float* rm = smem;               // [16*33]
      float* rs = smem + 528;
      int* ri = (int*)(smem + 1056);
      float* gmat = smem + 1584;      // [16*33]
      float* xl = smem + 2112;        // [32*161] fallback staging
      const int r = tid & 31, c16 = tid >> 5;

      // redundant online-softmax/argmax reduce over 157 tiles
      {
        float m = -FLT_MAX, s = 0.f; int ix = 0;
#pragma unroll
        for (int i = 0; i < 10; ++i) {
          int idx = c16 * 10 + i;
          bool v = (idx < NLOG);
          int ic = v ? idx : 0;
          float M = v ? ws[O_PM + ic * 32 + r] : -FLT_MAX;
          float S = v ? ws[O_PS + ic * 32 + r] : 0.f;
          int I = v ? __float_as_int(ws[O_PI + ic * 32 + r]) : 0;
          if (M > m) { s = s * expf(m - M) + S; m = M; ix = I; }
          else if (M > -FLT_MAX) { s += S * expf(M - m); }
        }
        rm[c16 * 33 + r] = m; rs[c16 * 33 + r] = s; ri[c16 * 33 + r] = ix;
      }
      __syncthreads();
      if (tid < 32) {
        float m = rm[tid], s = rs[tid]; int ix = ri[tid];
#pragma unroll
        for (int q = 1; q < 16; ++q) {
          float M = rm[q * 33 + tid], S = rs[q * 33 + tid]; int I = ri[q * 33 + tid];
          if (M > m) { s = s * expf(m - M) + S; m = M; ix = I; }
          else { s += S * expf(M - m); }
        }
        int pos = ix;
        int upd = (pos != 0) ? 1 : 0;
        int ntk = upd ? pos : s_ptok[tid];
        s_tok[tid] = ntk; s_upd[tid] = upd; s_ptok[tid] = ntk;
        if (bid == 0) {
          float sc = s_scores[tid];
          if (upd) sc -= logf(s);
          s_scores[tid] = sc;
          out[BB + (size_t)tid * TT + t] = upd ? (float)pos : 0.0f;
          if (t == TT - 1) out[tid] = sc;
        }
      }
      __syncthreads();

      // gate pre-activations for this block's 4 j rows (16 cols x 32 b = 512 threads)
      const int b = tid & 31, colg = tid >> 5;
      const int jl = colg >> 2, g = colg & 3;
      const int j = bid * 4 + jl;
      const int col = g * HH + j;
      float v = ws[O_HWH + col * 32 + b];
      if (use_table) {
        v += xwxb[(size_t)s_tok[b] * H4 + col];
      } else {
        v += bias[col];
        for (int st = 0; st < 4; ++st) {
          const int k0 = st * 160;
          __syncthreads();
          for (int i = tid; i < 32 * 160; i += 512) {
            int bb = i / 160, kk = i - bb * 160;
            xl[bb * 161 + kk] = embed[(size_t)s_tok[bb] * HH + k0 + kk];
          }
          __syncthreads();
#pragma unroll 8
          for (int k = 0; k < 160; ++k)
            v += xl[b * 161 + k] * Wx[(size_t)(k0 + k) * H4 + col];
        }
      }
      gmat[colg * 33 + b] = v;
      __syncthreads();
      if (tid < 128) {
        const int jl2 = tid >> 5, b2 = tid & 31;
        const int j2 = bid * 4 + jl2;
        float gi = gmat[(jl2 * 4 + 0) * 33 + b2];
        float gf = gmat[(jl2 * 4 + 1) * 33 + b2];
        float gg = gmat[(jl2 * 4 + 2) * 33 + b2];
        float go = gmat[(jl2 * 4 + 3) * 33 + b2];
        float ci = ws[O_CT + j2 * 32 + b2];
        float c2 = sigf(gf) * ci + sigf(gi) * tanhf(gg);
        float h2 = sigf(go) * tanhf(c2);
        float pv;
        if (s_upd[b2]) {
          ws[O_CT + j2 * 32 + b2] = c2;
          ws[O_HT + j2 * 32 + b2] = h2;
          ws[O_PNT + j2 * 32 + b2] = h2;
          pv = h2;
        } else {
          pv = ws[O_PNT + j2 * 32 + b2];
        }
        if (t + 1 < TT)
          ws[O_JOINT + j2 * 32 + b2] = tanhf(tn[((size_t)b2 * TT + (t + 1)) * HH + j2] + pv);
      }
    }
    epoch++; grid_bar(bar, epoch);
  }
}

extern "C" void kernel_launch(void* const* d_in, const int* in_sizes, int n_in,
                              void* d_out, int out_size, void* d_ws, size_t ws_size,
                              hipStream_t stream) {
  const float* tn    = (const float*)d_in[0];
  const float* embed = (const float*)d_in[1];
  const float* Wx    = (const float*)d_in[2];
  const float* Wh    = (const float*)d_in[3];
  const float* bias  = (const float*)d_in[4];
  const float* Wc    = (const float*)d_in[5];
  const float* bc    = (const float*)d_in[6];
  float* out = (float*)d_out;
  float* ws  = (float*)d_ws;

  const size_t need_table = (size_t)(O_XWXB + XWXB_ELEMS) * sizeof(float);
  const int use_table = (ws_size >= need_table) ? 1 : 0;

  if (use_table)
    hipLaunchKernelGGL(precompute_k, dim3(10, 313), dim3(256), 0, stream,
                       embed, Wx, bias, ws + O_XWXB);
  hipLaunchKernelGGL(init_k, dim3(80), dim3(256), 0, stream, tn, embed, Wx, bias, ws, use_table);
  hipLaunchKernelGGL(decode_k, dim3(NB), dim3(512), 0, stream,
                     tn, embed, Wx, bias, Wh, Wc, bc, out, ws, use_table);
}

// Round 4
// 47890.668 us; speedup vs baseline: 2.0965x; 2.0965x over previous
//
#include <hip/hip_runtime.h>
#include <float.h>

// Batched transducer greedy decode, B=32 T=1000 H=640 V=5000, fp32.
// Persistent kernel, 240 blocks x 512 thr, 2 grid barriers/step.
// Barrier: relaxed polling, release-on-arrival, acquire only where coherence is needed.
#define BB 32
#define TT 1000
#define HH 640
#define H4 2560
#define VV 5000
#define NLOG 157   // logits tiles, 32 cols each (last tile 8 valid)
#define NGATE 80   // gate blocks: strided 32-col Wh slice + 8 j-rows of state
#define NB   240   // 8 barrier groups x 30

// workspace layout (float offsets)
#define O_JOINT 0        // jointT[j][b]  (640x32)   cross-block
#define O_HT    20480    // hT[j][b]      (640x32)   cross-block
#define O_PM    40960    // partial max    [157*32]
#define O_PS    46080    // partial sumexp [157*32]
#define O_PI    51200    // partial argmax [157*32] (int bits)
#define O_BAR   56320    // barrier: 17 slots x 16 u32
#define O_CT    56704    // initial c (640x32) — consumed once at kernel start
#define O_PNT   77184    // initial out_PN (640x32) — consumed once
#define O_XWXB  97664    // embed@Wx + b  (5000x2560), optional
#define XWXB_ELEMS ((size_t)VV * (size_t)H4)

__device__ __forceinline__ float sigf(float x) { return 1.0f / (1.0f + expf(-x)); }

// grid barrier: relaxed poll; RELEASE on arrival (flushes this block's dirty stores);
// single ACQUIRE (L1/L2 invalidate) only if this block reads cross-block data next phase.
__device__ __forceinline__ void grid_bar(unsigned* bar, unsigned target, bool acq) {
  __syncthreads();
  if (threadIdx.x == 0) {
    const int g = (int)blockIdx.x / 30;
    unsigned* cnt  = bar + g * 16;
    unsigned* gen  = bar + (9 + g) * 16;
    unsigned a = __hip_atomic_fetch_add(cnt, 1u, __ATOMIC_RELEASE, __HIP_MEMORY_SCOPE_AGENT);
    if (a == 29u) {  // last of my group
      unsigned* root = bar + 8 * 16;
      unsigned r = __hip_atomic_fetch_add(root, 1u, __ATOMIC_ACQ_REL, __HIP_MEMORY_SCOPE_AGENT);
      if (r == 7u) {  // global last: reset counters, then release all gen lines
        __hip_atomic_store(root, 0u, __ATOMIC_RELAXED, __HIP_MEMORY_SCOPE_AGENT);
#pragma unroll
        for (int i = 0; i < 8; ++i)
          __hip_atomic_store(bar + i * 16, 0u, __ATOMIC_RELAXED, __HIP_MEMORY_SCOPE_AGENT);
#pragma unroll
        for (int i = 0; i < 8; ++i)
          __hip_atomic_store(bar + (9 + i) * 16, target, __ATOMIC_RELEASE, __HIP_MEMORY_SCOPE_AGENT);
      }
    }
    while (__hip_atomic_load(gen, __ATOMIC_RELAXED, __HIP_MEMORY_SCOPE_AGENT) < target)
      __builtin_amdgcn_s_sleep(1);
    if (acq)
      (void)__hip_atomic_load(gen, __ATOMIC_ACQUIRE, __HIP_MEMORY_SCOPE_AGENT);
  }
  __syncthreads();
}

// ---------------- precompute: xwxb[v][c] = sum_k embed[v][k]*Wx[k][c] + b[c]
__global__ __launch_bounds__(256) void precompute_k(const float* __restrict__ embed,
                                                    const float* __restrict__ Wx,
                                                    const float* __restrict__ bias,
                                                    float* __restrict__ xwxb) {
  __shared__ float embT[HH * 17];
  const int tid = threadIdx.x;
  const int v0 = blockIdx.y * 16;
  const int c0 = blockIdx.x * 256 + (tid & 63) * 4;
  const int vg = tid >> 6;
  for (int i = tid; i < 16 * 160; i += 256) {
    int vr = i / 160, kq = i - vr * 160;
    int v = v0 + vr; if (v >= VV) v = VV - 1;
    float4 e = *(const float4*)&embed[(size_t)v * HH + kq * 4];
    embT[(kq * 4 + 0) * 17 + vr] = e.x;
    embT[(kq * 4 + 1) * 17 + vr] = e.y;
    embT[(kq * 4 + 2) * 17 + vr] = e.z;
    embT[(kq * 4 + 3) * 17 + vr] = e.w;
  }
  __syncthreads();
  float acc[16];
#pragma unroll
  for (int i = 0; i < 16; ++i) acc[i] = 0.f;
#pragma unroll 4
  for (int k = 0; k < HH; ++k) {
    float4 wv = *(const float4*)&Wx[(size_t)k * H4 + c0];
#pragma unroll
    for (int i = 0; i < 4; ++i) {
      float e = embT[k * 17 + vg * 4 + i];
      acc[i * 4 + 0] += e * wv.x;
      acc[i * 4 + 1] += e * wv.y;
      acc[i * 4 + 2] += e * wv.z;
      acc[i * 4 + 3] += e * wv.w;
    }
  }
  float4 bv = *(const float4*)&bias[c0];
#pragma unroll
  for (int i = 0; i < 4; ++i) {
    int v = v0 + vg * 4 + i;
    if (v < VV) {
      float4 r;
      r.x = acc[i * 4 + 0] + bv.x; r.y = acc[i * 4 + 1] + bv.y;
      r.z = acc[i * 4 + 2] + bv.z; r.w = acc[i * 4 + 3] + bv.w;
      *(float4*)&xwxb[(size_t)v * H4 + c0] = r;
    }
  }
}

// ---------------- init: barrier zero + initial LSTM step (h0=c0=0, tok=0) + joint t=0
__global__ __launch_bounds__(256) void init_k(const float* __restrict__ tn,
                                              const float* __restrict__ embed,
                                              const float* __restrict__ Wx,
                                              const float* __restrict__ bias,
                                              float* ws, int use_table) {
  const int tid = threadIdx.x, bid = blockIdx.x;
  const int b = tid & 31, c8 = tid >> 5;
  const int j = bid * 8 + c8;
  if (bid == 0) {
    unsigned* bar = (unsigned*)(ws + O_BAR);
    for (int i = tid; i < 17 * 16; i += 256) bar[i] = 0u;
  }
  const float* xwxb = ws + O_XWXB;
  float g4[4];
  if (use_table) {
#pragma unroll
    for (int g = 0; g < 4; ++g) g4[g] = xwxb[g * HH + j];  // token 0 row
  } else {
#pragma unroll
    for (int g = 0; g < 4; ++g) g4[g] = bias[g * HH + j];
#pragma unroll 4
    for (int k = 0; k < HH; ++k) {
      float xv = embed[k];  // token 0 row
#pragma unroll
      for (int g = 0; g < 4; ++g) g4[g] += xv * Wx[(size_t)k * H4 + g * HH + j];
    }
  }
  float c1 = sigf(g4[0]) * tanhf(g4[2]);
  float h1 = sigf(g4[3]) * tanhf(c1);
  ws[O_CT + j * 32 + b] = c1;
  ws[O_HT + j * 32 + b] = h1;
  ws[O_PNT + j * 32 + b] = h1;
  ws[O_JOINT + j * 32 + b] = tanhf(tn[(size_t)b * TT * HH + j] + h1);
}

// ---------------- persistent decode kernel
__global__ __launch_bounds__(512, 2) void decode_k(const float* __restrict__ tn,
                                                   const float* __restrict__ embed,
                                                   const float* __restrict__ Wx,
                                                   const float* __restrict__ bias,
                                                   const float* __restrict__ Wh,
                                                   const float* __restrict__ Wc,
                                                   const float* __restrict__ bc,
                                                   float* __restrict__ out,
                                                   float* ws, int use_table) {
  __shared__ float smem[10288];   // scratch overlay
  __shared__ float hwh_s[1056];   // gate: hwh[lc(32) stride 33][b]  (persists A->B)
  __shared__ float c_s[256];      // gate: c state, 8 j x 32 b  (LDS-resident all steps)
  __shared__ float pn_s[256];     // gate: out_PN state
  __shared__ int s_tok[32];
  __shared__ int s_upd[32];
  __shared__ int s_ptok[32];
  __shared__ float s_scores[32];
  const int tid = threadIdx.x, bid = blockIdx.x;
  unsigned* bar = (unsigned*)(ws + O_BAR);
  const float* xwxb = ws + O_XWXB;
  const bool is_log = (bid < NLOG);
  const bool is_gate = (bid >= NLOG) && (bid < NLOG + NGATE);
  const int q = bid - NLOG;  // gate slice index

  if (tid < 32) { s_ptok[tid] = 0; s_scores[tid] = 0.f; }
  if (is_gate && tid < 256) {
    const int jj = tid >> 5, b = tid & 31;
    c_s[jj * 32 + b] = ws[O_CT + (q * 8 + jj) * 32 + b];
    pn_s[jj * 32 + b] = ws[O_PNT + (q * 8 + jj) * 32 + b];
  }
  __syncthreads();

  unsigned epoch = 0;
  for (int t = 0; t < TT; ++t) {
    float tnv = 0.f;  // gate: tn[b][t+1][8q+jj], prefetched (held across barrier 1)

    // ================= phase A =================
    if (is_log) {
      float* part = smem;                    // [8][32*34]
      float* lm = smem + 8704;
      float* lsv = smem + 8704 + 528;
      int* lix = (int*)(smem + 8704 + 1056);
      const int lane = tid & 63, wvv = tid >> 6;
      const int sub = lane >> 5, col = lane & 31;
      const int kbase = (wvv * 2 + sub) * 40;  // 16-way K split
      const int c = bid * 32 + col;
      const int cc = (c < VV) ? c : (VV - 1);
      const float* jb = ws + O_JOINT + kbase * 32;
      const float* wp = Wc + (size_t)kbase * VV + cc;
      float acc[32];
#pragma unroll
      for (int i = 0; i < 32; ++i) acc[i] = 0.f;
#pragma unroll 4
      for (int kk = 0; kk < 40; ++kk) {
        float w = wp[(size_t)kk * VV];
        const float4* jp = (const float4*)(jb + kk * 32);
#pragma unroll
        for (int r = 0; r < 8; ++r) {
          float4 j4 = jp[r];
          acc[r * 4 + 0] += j4.x * w; acc[r * 4 + 1] += j4.y * w;
          acc[r * 4 + 2] += j4.z * w; acc[r * 4 + 3] += j4.w * w;
        }
      }
#pragma unroll
      for (int i = 0; i < 32; ++i) acc[i] += __shfl_xor(acc[i], 32);
      if (sub == 0) {
        float* pb = part + wvv * 1088 + col * 34;
#pragma unroll
        for (int r2 = 0; r2 < 16; ++r2)
          *(float2*)&pb[r2 * 2] = make_float2(acc[r2 * 2], acc[r2 * 2 + 1]);
      }
      __syncthreads();
      const int b = tid & 31, colg = tid >> 5;
      float m = -FLT_MAX; int ix = 0;
      float lv[2];
#pragma unroll
      for (int i = 0; i < 2; ++i) {
        const int cl = colg * 2 + i;
        float s = 0.f;
#pragma unroll
        for (int qq = 0; qq < 8; ++qq) s += part[qq * 1088 + cl * 34 + b];
        int cg = bid * 32 + cl;
        float l = (cg < VV) ? s + bc[cg] : -FLT_MAX;
        lv[i] = l;
        if (l > m) { m = l; ix = cg; }
      }
      float e = 0.f;
      if (m > -FLT_MAX) {
#pragma unroll
        for (int i = 0; i < 2; ++i) e += expf(lv[i] - m);
      }
      lm[colg * 33 + b] = m; lsv[colg * 33 + b] = e; lix[colg * 33 + b] = ix;
      __syncthreads();
      if (tid < 32) {
        float m2 = lm[tid], s2 = lsv[tid]; int ix2 = lix[tid];
#pragma unroll
        for (int qq = 1; qq < 16; ++qq) {
          float M = lm[qq * 33 + tid], S = lsv[qq * 33 + tid]; int I = lix[qq * 33 + tid];
          if (M > m2) { s2 = s2 * expf(m2 - M) + S; m2 = M; ix2 = I; }
          else if (M > -FLT_MAX) { s2 += S * expf(M - m2); }
        }
        ws[O_PM + bid * 32 + tid] = m2;
        ws[O_PS + bid * 32 + tid] = s2;
        ws[O_PI + bid * 32 + tid] = __int_as_float(ix2);
      }
    } else if (is_gate) {
      if (tid < 256 && t + 1 < TT)
        tnv = tn[((size_t)(tid & 31) * TT + (t + 1)) * HH + q * 8 + (tid >> 5)];
      float* part = smem;
      const int lane = tid & 63, wvv = tid >> 6;
      const int sub = lane >> 5, lc = lane & 31;
      const int kbase = (wvv * 2 + sub) * 40;
      const int wcol = (lc >> 3) * HH + q * 8 + (lc & 7);  // strided col slice
      const float* hb = ws + O_HT + kbase * 32;
      const float* wp = Wh + (size_t)kbase * H4 + wcol;
      float acc[32];
#pragma unroll
      for (int i = 0; i < 32; ++i) acc[i] = 0.f;
#pragma unroll 4
      for (int kk = 0; kk < 40; ++kk) {
        float w = wp[(size_t)kk * H4];
        const float4* jp = (const float4*)(hb + kk * 32);
#pragma unroll
        for (int r = 0; r < 8; ++r) {
          float4 j4 = jp[r];
          acc[r * 4 + 0] += j4.x * w; acc[r * 4 + 1] += j4.y * w;
          acc[r * 4 + 2] += j4.z * w; acc[r * 4 + 3] += j4.w * w;
        }
      }
#pragma unroll
      for (int i = 0; i < 32; ++i) acc[i] += __shfl_xor(acc[i], 32);
      if (sub == 0) {
        float* pb = part + wvv * 1088 + lc * 34;
#pragma unroll
        for (int r2 = 0; r2 < 16; ++r2)
          *(float2*)&pb[r2 * 2] = make_float2(acc[r2 * 2], acc[r2 * 2 + 1]);
      }
      __syncthreads();
      const int b = tid & 31, colg = tid >> 5;
#pragma unroll
      for (int i = 0; i < 2; ++i) {
        const int cl = colg * 2 + i;
        float s = 0.f;
#pragma unroll
        for (int qq = 0; qq < 8; ++qq) s += part[qq * 1088 + cl * 34 + b];
        hwh_s[cl * 33 + b] = s;  // stays in LDS — no global round-trip
      }
    }
    epoch++;
    grid_bar(bar, epoch, /*acq=*/is_gate);  // gate blocks read partials next

    // ================= phase B (gate blocks only) =================
    if (is_gate) {
      float* rm = smem;               // [16*33]
      float* rs = smem + 528;
      int* ri = (int*)(smem + 1056);
      float* gmat = smem + 1584;      // [32*33]
      float* xl = smem + 2640;        // [32*161] fallback staging
      const int r = tid & 31, c16 = tid >> 5;
      {
        float m = -FLT_MAX, s = 0.f; int ix = 0;
#pragma unroll
        for (int i = 0; i < 10; ++i) {
          int idx = c16 * 10 + i;
          bool v = (idx < NLOG);
          int ic = v ? idx : 0;
          float M = v ? ws[O_PM + ic * 32 + r] : -FLT_MAX;
          float S = v ? ws[O_PS + ic * 32 + r] : 0.f;
          int I = v ? __float_as_int(ws[O_PI + ic * 32 + r]) : 0;
          if (M > m) { s = s * expf(m - M) + S; m = M; ix = I; }
          else if (M > -FLT_MAX) { s += S * expf(M - m); }
        }
        rm[c16 * 33 + r] = m; rs[c16 * 33 + r] = s; ri[c16 * 33 + r] = ix;
      }
      __syncthreads();
      if (tid < 32) {
        float m = rm[tid], s = rs[tid]; int ix = ri[tid];
#pragma unroll
        for (int qq = 1; qq < 16; ++qq) {
          float M = rm[qq * 33 + tid], S = rs[qq * 33 + tid]; int I = ri[qq * 33 + tid];
          if (M > m) { s = s * expf(m - M) + S; m = M; ix = I; }
          else { s += S * expf(M - m); }
        }
        int pos = ix;
        int upd = (pos != 0) ? 1 : 0;
        int ntk = upd ? pos : s_ptok[tid];
        s_tok[tid] = ntk; s_upd[tid] = upd; s_ptok[tid] = ntk;
        if (bid == NLOG) {  // emitter
          float sc = s_scores[tid];
          if (upd) sc -= logf(s);
          s_scores[tid] = sc;
          out[BB + (size_t)tid * TT + t] = upd ? (float)pos : 0.0f;
          if (t == TT - 1) out[tid] = sc;
        }
      }
      __syncthreads();

      // gate pre-activations for the block's 32 strided cols
      const int b = tid & 31;
      float gv[2];
#pragma unroll
      for (int h = 0; h < 2; ++h) {
        int lc = (tid >> 5) + h * 16;
        int wcol = (lc >> 3) * HH + q * 8 + (lc & 7);
        float v = hwh_s[lc * 33 + b];
        if (use_table) v += xwxb[(size_t)s_tok[b] * H4 + wcol];
        else v += bias[wcol];
        gv[h] = v;
      }
      if (!use_table) {
        for (int st = 0; st < 4; ++st) {
          const int k0 = st * 160;
          __syncthreads();
          for (int i = tid; i < 32 * 160; i += 512) {
            int bb = i / 160, kk = i - bb * 160;
            xl[bb * 161 + kk] = embed[(size_t)s_tok[bb] * HH + k0 + kk];
          }
          __syncthreads();
          for (int k = 0; k < 160; ++k) {
            float xv = xl[b * 161 + k];
#pragma unroll
            for (int h = 0; h < 2; ++h) {
              int lc = (tid >> 5) + h * 16;
              int wcol = (lc >> 3) * HH + q * 8 + (lc & 7);
              gv[h] += xv * Wx[(size_t)(k0 + k) * H4 + wcol];
            }
          }
        }
      }
#pragma unroll
      for (int h = 0; h < 2; ++h) {
        int lc = (tid >> 5) + h * 16;
        gmat[lc * 33 + b] = gv[h];
      }
      __syncthreads();
      if (tid < 256) {
        const int jj = tid >> 5, b2 = tid & 31;
        float gi = gmat[(0 * 8 + jj) * 33 + b2];
        float gf = gmat[(1 * 8 + jj) * 33 + b2];
        float gg = gmat[(2 * 8 + jj) * 33 + b2];
        float go = gmat[(3 * 8 + jj) * 33 + b2];
        float cold = c_s[jj * 32 + b2];
        float c2 = sigf(gf) * cold + sigf(gi) * tanhf(gg);
        float h2 = sigf(go) * tanhf(c2);
        float pv;
        if (s_upd[b2]) {
          c_s[jj * 32 + b2] = c2;
          pn_s[jj * 32 + b2] = h2;
          ws[O_HT + (q * 8 + jj) * 32 + b2] = h2;  // cross-block: released at barrier
          pv = h2;
        } else {
          pv = pn_s[jj * 32 + b2];
        }
        if (t + 1 < TT)
          ws[O_JOINT + (q * 8 + jj) * 32 + b2] = tanhf(tnv + pv);
      }
    }
    epoch++;
    grid_bar(bar, epoch, /*acq=*/is_log || is_gate);  // next A reads jointT / hT
  }
}

extern "C" void kernel_launch(void* const* d_in, const int* in_sizes, int n_in,
                              void* d_out, int out_size, void* d_ws, size_t ws_size,
                              hipStream_t stream) {
  const float* tn    = (const float*)d_in[0];
  const float* embed = (const float*)d_in[1];
  const float* Wx    = (const float*)d_in[2];
  const float* Wh    = (const float*)d_in[3];
  const float* bias  = (const float*)d_in[4];
  const float* Wc    = (const float*)d_in[5];
  const float* bc    = (const float*)d_in[6];
  float* out = (float*)d_out;
  float* ws  = (float*)d_ws;

  const size_t need_table = (size_t)(O_XWXB + XWXB_ELEMS) * sizeof(float);
  const int use_table = (ws_size >= need_table) ? 1 : 0;

  if (use_table)
    hipLaunchKernelGGL(precompute_k, dim3(10, 313), dim3(256), 0, stream,
                       embed, Wx, bias, ws + O_XWXB);
  hipLaunchKernelGGL(init_k, dim3(80), dim3(256), 0, stream, tn, embed, Wx, bias, ws, use_table);
  hipLaunchKernelGGL(decode_k, dim3(NB), dim3(512), 0, stream,
                     tn, embed, Wx, bias, Wh, Wc, bc, out, ws, use_table);
}

// Round 5
// 46676.825 us; speedup vs baseline: 2.1511x; 1.0260x over previous
//
#include <hip/hip_runtime.h>
#include <float.h>

// Batched transducer greedy decode, B=32 T=1000 H=640 V=5000, fp32.
// Persistent kernel, 240 blocks x 512 thr, 2 grid barriers/step.
// Key idea: per-block weight slices (Wc/Wh) staged in LDS once -> immune to the
// per-step agent-scope acquire that invalidates L2 for cross-block coherence.
#define BB 32
#define TT 1000
#define HH 640
#define H4 2560
#define VV 5000
#define NLOG 157   // logits tiles, 32 cols each (last tile 8 valid)
#define NGATE 80   // gate blocks: strided 32-col Wh slice + 8 j-rows of state
#define NB   240   // 8 barrier groups x 30

// workspace layout (float offsets)
#define O_JOINT 0        // jointT[j][b]  (640x32)   cross-block
#define O_HT    20480    // hT[j][b]      (640x32)   cross-block
#define O_PM    40960    // partial max    [157*32]
#define O_PS    46080    // partial sumexp [157*32]
#define O_PI    51200    // partial argmax [157*32] (int bits)
#define O_BAR   56320    // barrier: 17 slots x 16 u32
#define O_CT    56704    // initial c (640x32) — consumed once at kernel start
#define O_PNT   77184    // initial out_PN (640x32) — consumed once
#define O_XWXB  97664    // embed@Wx + b  (5000x2560), optional
#define XWXB_ELEMS ((size_t)VV * (size_t)H4)

__device__ __forceinline__ float sigf(float x) { return 1.0f / (1.0f + expf(-x)); }

// grid barrier: relaxed poll; RELEASE on arrival; single ACQUIRE only when needed.
__device__ __forceinline__ void grid_bar(unsigned* bar, unsigned target, bool acq) {
  __syncthreads();
  if (threadIdx.x == 0) {
    const int g = (int)blockIdx.x / 30;
    unsigned* cnt  = bar + g * 16;
    unsigned* gen  = bar + (9 + g) * 16;
    unsigned a = __hip_atomic_fetch_add(cnt, 1u, __ATOMIC_RELEASE, __HIP_MEMORY_SCOPE_AGENT);
    if (a == 29u) {
      unsigned* root = bar + 8 * 16;
      unsigned r = __hip_atomic_fetch_add(root, 1u, __ATOMIC_ACQ_REL, __HIP_MEMORY_SCOPE_AGENT);
      if (r == 7u) {
        __hip_atomic_store(root, 0u, __ATOMIC_RELAXED, __HIP_MEMORY_SCOPE_AGENT);
#pragma unroll
        for (int i = 0; i < 8; ++i)
          __hip_atomic_store(bar + i * 16, 0u, __ATOMIC_RELAXED, __HIP_MEMORY_SCOPE_AGENT);
#pragma unroll
        for (int i = 0; i < 8; ++i)
          __hip_atomic_store(bar + (9 + i) * 16, target, __ATOMIC_RELEASE, __HIP_MEMORY_SCOPE_AGENT);
      }
    }
    while (__hip_atomic_load(gen, __ATOMIC_RELAXED, __HIP_MEMORY_SCOPE_AGENT) < target)
      __builtin_amdgcn_s_sleep(1);
    if (acq)
      (void)__hip_atomic_load(gen, __ATOMIC_ACQUIRE, __HIP_MEMORY_SCOPE_AGENT);
  }
  __syncthreads();
}

// ---------------- precompute: xwxb[v][c] = sum_k embed[v][k]*Wx[k][c] + b[c]
__global__ __launch_bounds__(256) void precompute_k(const float* __restrict__ embed,
                                                    const float* __restrict__ Wx,
                                                    const float* __restrict__ bias,
                                                    float* __restrict__ xwxb) {
  __shared__ float embT[HH * 17];
  const int tid = threadIdx.x;
  const int v0 = blockIdx.y * 16;
  const int c0 = blockIdx.x * 256 + (tid & 63) * 4;
  const int vg = tid >> 6;
  for (int i = tid; i < 16 * 160; i += 256) {
    int vr = i / 160, kq = i - vr * 160;
    int v = v0 + vr; if (v >= VV) v = VV - 1;
    float4 e = *(const float4*)&embed[(size_t)v * HH + kq * 4];
    embT[(kq * 4 + 0) * 17 + vr] = e.x;
    embT[(kq * 4 + 1) * 17 + vr] = e.y;
    embT[(kq * 4 + 2) * 17 + vr] = e.z;
    embT[(kq * 4 + 3) * 17 + vr] = e.w;
  }
  __syncthreads();
  float acc[16];
#pragma unroll
  for (int i = 0; i < 16; ++i) acc[i] = 0.f;
#pragma unroll 4
  for (int k = 0; k < HH; ++k) {
    float4 wv = *(const float4*)&Wx[(size_t)k * H4 + c0];
#pragma unroll
    for (int i = 0; i < 4; ++i) {
      float e = embT[k * 17 + vg * 4 + i];
      acc[i * 4 + 0] += e * wv.x;
      acc[i * 4 + 1] += e * wv.y;
      acc[i * 4 + 2] += e * wv.z;
      acc[i * 4 + 3] += e * wv.w;
    }
  }
  float4 bv = *(const float4*)&bias[c0];
#pragma unroll
  for (int i = 0; i < 4; ++i) {
    int v = v0 + vg * 4 + i;
    if (v < VV) {
      float4 r;
      r.x = acc[i * 4 + 0] + bv.x; r.y = acc[i * 4 + 1] + bv.y;
      r.z = acc[i * 4 + 2] + bv.z; r.w = acc[i * 4 + 3] + bv.w;
      *(float4*)&xwxb[(size_t)v * H4 + c0] = r;
    }
  }
}

// ---------------- init: barrier zero + initial LSTM step (h0=c0=0, tok=0) + joint t=0
__global__ __launch_bounds__(256) void init_k(const float* __restrict__ tn,
                                              const float* __restrict__ embed,
                                              const float* __restrict__ Wx,
                                              const float* __restrict__ bias,
                                              float* ws, int use_table) {
  const int tid = threadIdx.x, bid = blockIdx.x;
  const int b = tid & 31, c8 = tid >> 5;
  const int j = bid * 8 + c8;
  if (bid == 0) {
    unsigned* bar = (unsigned*)(ws + O_BAR);
    for (int i = tid; i < 17 * 16; i += 256) bar[i] = 0u;
  }
  const float* xwxb = ws + O_XWXB;
  float g4[4];
  if (use_table) {
#pragma unroll
    for (int g = 0; g < 4; ++g) g4[g] = xwxb[g * HH + j];  // token 0 row
  } else {
#pragma unroll
    for (int g = 0; g < 4; ++g) g4[g] = bias[g * HH + j];
#pragma unroll 4
    for (int k = 0; k < HH; ++k) {
      float xv = embed[k];  // token 0 row
#pragma unroll
      for (int g = 0; g < 4; ++g) g4[g] += xv * Wx[(size_t)k * H4 + g * HH + j];
    }
  }
  float c1 = sigf(g4[0]) * tanhf(g4[2]);
  float h1 = sigf(g4[3]) * tanhf(c1);
  ws[O_CT + j * 32 + b] = c1;
  ws[O_HT + j * 32 + b] = h1;
  ws[O_PNT + j * 32 + b] = h1;
  ws[O_JOINT + j * 32 + b] = tanhf(tn[(size_t)b * TT * HH + j] + h1);
}

// ---------------- persistent decode kernel
__global__ __launch_bounds__(512) void decode_k(const float* __restrict__ tn,
                                                const float* __restrict__ embed,
                                                const float* __restrict__ Wx,
                                                const float* __restrict__ bias,
                                                const float* __restrict__ Wh,
                                                const float* __restrict__ Wc,
                                                const float* __restrict__ bc,
                                                float* __restrict__ out,
                                                float* ws, int use_table) {
  __shared__ float w_s[20480];    // 80 KB: this block's weight slice (Wc or Wh), LDS-resident
  __shared__ float smem[10288];   // scratch overlay
  __shared__ float hwh_s[1056];   // gate: hwh[lc(32) stride 33][b]  (persists A->B)
  __shared__ float c_s[256];      // gate: c state (LDS-resident)
  __shared__ float pn_s[256];     // gate: out_PN state
  __shared__ int s_tok[32];
  __shared__ int s_upd[32];
  __shared__ int s_ptok[32];
  __shared__ float s_scores[32];
  const int tid = threadIdx.x, bid = blockIdx.x;
  unsigned* bar = (unsigned*)(ws + O_BAR);
  const float* xwxb = ws + O_XWXB;
  const bool is_log = (bid < NLOG);
  const bool is_gate = (bid >= NLOG) && (bid < NLOG + NGATE);
  const int q = bid - NLOG;  // gate slice index

  if (tid < 32) { s_ptok[tid] = 0; s_scores[tid] = 0.f; }
  // stage weight slice into LDS once (immune to later L2 invalidates)
  if (is_log) {
    const int c0 = bid * 32;
    for (int i = tid; i < 20480; i += 512) {
      int k = i >> 5, cl = i & 31;
      int c = c0 + cl; if (c >= VV) c = VV - 1;
      w_s[i] = Wc[(size_t)k * VV + c];
    }
  } else if (is_gate) {
    for (int i = tid; i < 20480; i += 512) {
      int k = i >> 5, lc = i & 31;
      int wcol = (lc >> 3) * HH + q * 8 + (lc & 7);
      w_s[i] = Wh[(size_t)k * H4 + wcol];
    }
    if (tid < 256) {
      const int jj = tid >> 5, b = tid & 31;
      c_s[jj * 32 + b] = ws[O_CT + (q * 8 + jj) * 32 + b];
      pn_s[jj * 32 + b] = ws[O_PNT + (q * 8 + jj) * 32 + b];
    }
  }
  __syncthreads();

  unsigned epoch = 0;
  for (int t = 0; t < TT; ++t) {
    float tnv = 0.f;  // gate: tn[b][t+1][8q+jj], prefetched (held across barrier 1)

    // ================= phase A =================
    if (is_log) {
      float* part = smem;                    // [8][32*34]
      float* lm = smem + 8704;
      float* lsv = smem + 8704 + 528;
      int* lix = (int*)(smem + 8704 + 1056);
      const int lane = tid & 63, wvv = tid >> 6;
      const int sub = lane >> 5, col = lane & 31;
      const int kbase = (wvv * 2 + sub) * 40;  // 16-way K split
      const float* jb = ws + O_JOINT + kbase * 32;
      const float* wl = w_s + kbase * 32 + col;
      float acc[32];
#pragma unroll
      for (int i = 0; i < 32; ++i) acc[i] = 0.f;
#pragma unroll 4
      for (int kk = 0; kk < 40; ++kk) {
        float w = wl[kk * 32];
        const float4* jp = (const float4*)(jb + kk * 32);
#pragma unroll
        for (int r = 0; r < 8; ++r) {
          float4 j4 = jp[r];
          acc[r * 4 + 0] += j4.x * w; acc[r * 4 + 1] += j4.y * w;
          acc[r * 4 + 2] += j4.z * w; acc[r * 4 + 3] += j4.w * w;
        }
      }
#pragma unroll
      for (int i = 0; i < 32; ++i) acc[i] += __shfl_xor(acc[i], 32);
      if (sub == 0) {
        float* pb = part + wvv * 1088 + col * 34;
#pragma unroll
        for (int r2 = 0; r2 < 16; ++r2)
          *(float2*)&pb[r2 * 2] = make_float2(acc[r2 * 2], acc[r2 * 2 + 1]);
      }
      __syncthreads();
      const int b = tid & 31, colg = tid >> 5;
      float m = -FLT_MAX; int ix = 0;
      float lv[2];
#pragma unroll
      for (int i = 0; i < 2; ++i) {
        const int cl = colg * 2 + i;
        float s = 0.f;
#pragma unroll
        for (int qq = 0; qq < 8; ++qq) s += part[qq * 1088 + cl * 34 + b];
        int cg = bid * 32 + cl;
        float l = (cg < VV) ? s + bc[cg] : -FLT_MAX;
        lv[i] = l;
        if (l > m) { m = l; ix = cg; }
      }
      float e = 0.f;
      if (m > -FLT_MAX) {
#pragma unroll
        for (int i = 0; i < 2; ++i) e += expf(lv[i] - m);
      }
      lm[colg * 33 + b] = m; lsv[colg * 33 + b] = e; lix[colg * 33 + b] = ix;
      __syncthreads();
      if (tid < 32) {
        float m2 = lm[tid], s2 = lsv[tid]; int ix2 = lix[tid];
#pragma unroll
        for (int qq = 1; qq < 16; ++qq) {
          float M = lm[qq * 33 + tid], S = lsv[qq * 33 + tid]; int I = lix[qq * 33 + tid];
          if (M > m2) { s2 = s2 * expf(m2 - M) + S; m2 = M; ix2 = I; }
          else if (M > -FLT_MAX) { s2 += S * expf(M - m2); }
        }
        ws[O_PM + bid * 32 + tid] = m2;
        ws[O_PS + bid * 32 + tid] = s2;
        ws[O_PI + bid * 32 + tid] = __int_as_float(ix2);
      }
    } else if (is_gate) {
      if (tid < 256 && t + 1 < TT)
        tnv = tn[((size_t)(tid & 31) * TT + (t + 1)) * HH + q * 8 + (tid >> 5)];
      float* part = smem;
      const int lane = tid & 63, wvv = tid >> 6;
      const int sub = lane >> 5, lc = lane & 31;
      const int kbase = (wvv * 2 + sub) * 40;
      const float* hb = ws + O_HT + kbase * 32;
      const float* wl = w_s + kbase * 32 + lc;
      float acc[32];
#pragma unroll
      for (int i = 0; i < 32; ++i) acc[i] = 0.f;
#pragma unroll 4
      for (int kk = 0; kk < 40; ++kk) {
        float w = wl[kk * 32];
        const float4* jp = (const float4*)(hb + kk * 32);
#pragma unroll
        for (int r = 0; r < 8; ++r) {
          float4 j4 = jp[r];
          acc[r * 4 + 0] += j4.x * w; acc[r * 4 + 1] += j4.y * w;
          acc[r * 4 + 2] += j4.z * w; acc[r * 4 + 3] += j4.w * w;
        }
      }
#pragma unroll
      for (int i = 0; i < 32; ++i) acc[i] += __shfl_xor(acc[i], 32);
      if (sub == 0) {
        float* pb = part + wvv * 1088 + lc * 34;
#pragma unroll
        for (int r2 = 0; r2 < 16; ++r2)
          *(float2*)&pb[r2 * 2] = make_float2(acc[r2 * 2], acc[r2 * 2 + 1]);
      }
      __syncthreads();
      const int b = tid & 31, colg = tid >> 5;
#pragma unroll
      for (int i = 0; i < 2; ++i) {
        const int cl = colg * 2 + i;
        float s = 0.f;
#pragma unroll
        for (int qq = 0; qq < 8; ++qq) s += part[qq * 1088 + cl * 34 + b];
        hwh_s[cl * 33 + b] = s;  // stays in LDS — no global round-trip
      }
    }
    epoch++;
    grid_bar(bar, epoch, /*acq=*/is_gate);  // gate blocks read partials next

    // ================= phase B (gate blocks only) =================
    if (is_gate) {
      float* rm = smem;               // [16*33]
      float* rs = smem + 528;
      int* ri = (int*)(smem + 1056);
      float* gmat = smem + 1584;      // [32*33]
      float* xl = smem + 2640;        // [32*161] fallback staging
      const int r = tid & 31, c16 = tid >> 5;
      {
        float m = -FLT_MAX, s = 0.f; int ix = 0;
#pragma unroll
        for (int i = 0; i < 10; ++i) {
          int idx = c16 * 10 + i;
          bool v = (idx < NLOG);
          int ic = v ? idx : 0;
          float M = v ? ws[O_PM + ic * 32 + r] : -FLT_MAX;
          float S = v ? ws[O_PS + ic * 32 + r] : 0.f;
          int I = v ? __float_as_int(ws[O_PI + ic * 32 + r]) : 0;
          if (M > m) { s = s * expf(m - M) + S; m = M; ix = I; }
          else if (M > -FLT_MAX) { s += S * expf(M - m); }
        }
        rm[c16 * 33 + r] = m; rs[c16 * 33 + r] = s; ri[c16 * 33 + r] = ix;
      }
      __syncthreads();
      if (tid < 32) {
        float m = rm[tid], s = rs[tid]; int ix = ri[tid];
#pragma unroll
        for (int qq = 1; qq < 16; ++qq) {
          float M = rm[qq * 33 + tid], S = rs[qq * 33 + tid]; int I = ri[qq * 33 + tid];
          if (M > m) { s = s * expf(m - M) + S; m = M; ix = I; }
          else { s += S * expf(M - m); }
        }
        int pos = ix;
        int upd = (pos != 0) ? 1 : 0;
        int ntk = upd ? pos : s_ptok[tid];
        s_tok[tid] = ntk; s_upd[tid] = upd; s_ptok[tid] = ntk;
        if (bid == NLOG) {  // emitter
          float sc = s_scores[tid];
          if (upd) sc -= logf(s);
          s_scores[tid] = sc;
          out[BB + (size_t)tid * TT + t] = upd ? (float)pos : 0.0f;
          if (t == TT - 1) out[tid] = sc;
        }
      }
      __syncthreads();

      // gate pre-activations for the block's 32 strided cols
      const int b = tid & 31;
      float gv[2];
#pragma unroll
      for (int h = 0; h < 2; ++h) {
        int lc = (tid >> 5) + h * 16;
        int wcol = (lc >> 3) * HH + q * 8 + (lc & 7);
        float v = hwh_s[lc * 33 + b];
        if (use_table) v += xwxb[(size_t)s_tok[b] * H4 + wcol];
        else v += bias[wcol];
        gv[h] = v;
      }
      if (!use_table) {
        for (int st = 0; st < 4; ++st) {
          const int k0 = st * 160;
          __syncthreads();
          for (int i = tid; i < 32 * 160; i += 512) {
            int bb = i / 160, kk = i - bb * 160;
            xl[bb * 161 + kk] = embed[(size_t)s_tok[bb] * HH + k0 + kk];
          }
          __syncthreads();
          for (int k = 0; k < 160; ++k) {
            float xv = xl[b * 161 + k];
#pragma unroll
            for (int h = 0; h < 2; ++h) {
              int lc = (tid >> 5) + h * 16;
              int wcol = (lc >> 3) * HH + q * 8 + (lc & 7);
              gv[h] += xv * Wx[(size_t)(k0 + k) * H4 + wcol];
            }
          }
        }
      }
#pragma unroll
      for (int h = 0; h < 2; ++h) {
        int lc = (tid >> 5) + h * 16;
        gmat[lc * 33 + b] = gv[h];
      }
      __syncthreads();
      if (tid < 256) {
        const int jj = tid >> 5, b2 = tid & 31;
        float gi = gmat[(0 * 8 + jj) * 33 + b2];
        float gf = gmat[(1 * 8 + jj) * 33 + b2];
        float gg = gmat[(2 * 8 + jj) * 33 + b2];
        float go = gmat[(3 * 8 + jj) * 33 + b2];
        float cold = c_s[jj * 32 + b2];
        float c2 = sigf(gf) * cold + sigf(gi) * tanhf(gg);
        float h2 = sigf(go) * tanhf(c2);
        float pv;
        if (s_upd[b2]) {
          c_s[jj * 32 + b2] = c2;
          pn_s[jj * 32 + b2] = h2;
          ws[O_HT + (q * 8 + jj) * 32 + b2] = h2;  // cross-block: released at barrier
          pv = h2;
        } else {
          pv = pn_s[jj * 32 + b2];
        }
        if (t + 1 < TT)
          ws[O_JOINT + (q * 8 + jj) * 32 + b2] = tanhf(tnv + pv);
      }
    }
    epoch++;
    grid_bar(bar, epoch, /*acq=*/is_log || is_gate);  // next A reads jointT / hT
  }
}

extern "C" void kernel_launch(void* const* d_in, const int* in_sizes, int n_in,
                              void* d_out, int out_size, void* d_ws, size_t ws_size,
                              hipStream_t stream) {
  const float* tn    = (const float*)d_in[0];
  const float* embed = (const float*)d_in[1];
  const float* Wx    = (const float*)d_in[2];
  const float* Wh    = (const float*)d_in[3];
  const float* bias  = (const float*)d_in[4];
  const float* Wc    = (const float*)d_in[5];
  const float* bc    = (const float*)d_in[6];
  float* out = (float*)d_out;
  float* ws  = (float*)d_ws;

  const size_t need_table = (size_t)(O_XWXB + XWXB_ELEMS) * sizeof(float);
  const int use_table = (ws_size >= need_table) ? 1 : 0;

  if (use_table)
    hipLaunchKernelGGL(precompute_k, dim3(10, 313), dim3(256), 0, stream,
                       embed, Wx, bias, ws + O_XWXB);
  hipLaunchKernelGGL(init_k, dim3(80), dim3(256), 0, stream, tn, embed, Wx, bias, ws, use_table);
  hipLaunchKernelGGL(decode_k, dim3(NB), dim3(512), 0, stream,
                     tn, embed, Wx, bias, Wh, Wc, bc, out, ws, use_table);
}